// Round 11
// baseline (478.651 us; speedup 1.0000x reference)
//
#include <hip/hip_runtime.h>
#include <math.h>

// Pipeline (d_out doubles as scratch for the A hi/lo split = exactly 134.2MB):
//   k0 split_a:   A fp32 [65536,512] -> Ah,Al fp16 (row-major) in d_out
//   k1 gemm:      qkv[65536,1536] = (Ah+Al) @ fp16(W)^T + bias   (in d_ws)
//   k2 scramble:  qkv -> out (overwrites d_out; verified round 1)
//
// r11 gemm geometry: block 128x256, 4 waves of 128x64 (1M x 4N), BK=32.
// LDS/buffer (halves): Ah [0,4096) Al [4096,8192) W [8192,16384); dbuf 64KB.
// Wave-tile 128x64 cuts ds_read bytes/MFMA 0.375 -> 0.31 and halves
// barriers/MFMA vs 64x64 waves (LDS-BW + barrier-granularity limiter).

typedef _Float16 half8 __attribute__((ext_vector_type(8)));
typedef __fp16 fp16x2 __attribute__((ext_vector_type(2)));
typedef float f32x4 __attribute__((ext_vector_type(4)));

__device__ __forceinline__ half8 pk8(const float4 x, const float4 y) {
    fp16x2 a = __builtin_amdgcn_cvt_pkrtz(x.x, x.y);
    fp16x2 b = __builtin_amdgcn_cvt_pkrtz(x.z, x.w);
    fp16x2 c = __builtin_amdgcn_cvt_pkrtz(y.x, y.y);
    fp16x2 d = __builtin_amdgcn_cvt_pkrtz(y.z, y.w);
    half8 r;
    r[0] = (_Float16)a[0]; r[1] = (_Float16)a[1];
    r[2] = (_Float16)b[0]; r[3] = (_Float16)b[1];
    r[4] = (_Float16)c[0]; r[5] = (_Float16)c[1];
    r[6] = (_Float16)d[0]; r[7] = (_Float16)d[1];
    return r;
}
__device__ __forceinline__ void pk8_hilo(const float4 x, const float4 y,
                                         half8& h, half8& l) {
    h = pk8(x, y);
    float4 rx, ry;
    rx.x = x.x - (float)h[0]; rx.y = x.y - (float)h[1];
    rx.z = x.z - (float)h[2]; rx.w = x.w - (float)h[3];
    ry.x = y.x - (float)h[4]; ry.y = y.y - (float)h[5];
    ry.z = y.z - (float)h[6]; ry.w = y.w - (float)h[7];
    l = pk8(rx, ry);
}

__device__ __forceinline__ void gload_lds16(const void* g, void* l) {
    __builtin_amdgcn_global_load_lds(
        (const __attribute__((address_space(1))) unsigned int*)g,
        (__attribute__((address_space(3))) unsigned int*)l, 16, 0, 0);
}

// ---------------------------------------------------------------------------
// k0: streaming split A -> fp16 hi/lo (row-major, same indexing as A)
// ---------------------------------------------------------------------------
__global__ __launch_bounds__(256) void split_a(
    const float* __restrict__ A,
    _Float16* __restrict__ hi, _Float16* __restrict__ lo)
{
    const size_t i = (size_t)blockIdx.x * 256 + threadIdx.x;   // 8 floats each
    const float4 x = *reinterpret_cast<const float4*>(A + i * 8);
    const float4 y = *reinterpret_cast<const float4*>(A + i * 8 + 4);
    half8 h, l;
    pk8_hilo(x, y, h, l);
    *reinterpret_cast<half8*>(hi + i * 8) = h;
    *reinterpret_cast<half8*>(lo + i * 8) = l;
}

// ---------------------------------------------------------------------------
// k1: C[65536,1536] = A @ W^T + bias.  BM=128, BN=256, BK=32, 4 waves.
// Swizzle: 16B chunk c of row r at phys c ^ ((r>>1)&3) — measured 0 conflicts.
// A: global_load_lds with XOR on the per-lane GLOBAL source (rule 21).
// W: reg-staged depth-2 + cvt_pkrtz (r10-proven), vmcnt(8) counted drain.
// ---------------------------------------------------------------------------
__global__ __launch_bounds__(256, 2) void gemm_qkv_w256(
    const _Float16* __restrict__ Ah, const _Float16* __restrict__ Al,
    const float* __restrict__ W, const float* __restrict__ bias,
    float* __restrict__ C)
{
    __shared__ __align__(16) _Float16 lds[32768];   // 2 x 32 KB = 64 KB

    const int lin = blockIdx.x;                      // 3072 blocks, %8==0
    const int swz = (lin & 7) * 384 + (lin >> 3);
    const int nt = swz % 6, mt = swz / 6;            // nt fastest: A L2-reuse
    const int row0 = mt * 128, col0 = nt * 256;

    const int tid = threadIdx.x, wid = tid >> 6, lane = tid & 63;
    const int l15 = lane & 15, kq = lane >> 4;

    // ---- A staging (verbatim r10): wave wid owns 1KB segs s0,s0+1 of hi & lo
    const int s0  = wid * 2;
    const int rA0 = s0 * 16 + (lane >> 2);
    const int rA1 = rA0 + 16;
    const int c0  = (lane & 3) ^ ((rA0 >> 1) & 3);
    const int c1  = (lane & 3) ^ ((rA1 >> 1) & 3);
    const _Float16* gh0 = Ah + (size_t)(row0 + rA0) * 512 + c0 * 8;
    const _Float16* gh1 = Ah + (size_t)(row0 + rA1) * 512 + c1 * 8;
    const _Float16* gl0 = Al + (size_t)(row0 + rA0) * 512 + c0 * 8;
    const _Float16* gl1 = Al + (size_t)(row0 + rA1) * 512 + c1 * 8;

    // ---- W staging: thread tid covers W-tile row rw = tid (256 rows), all 32 k
    const int rw = tid;
    const float* Wg = W + (size_t)(col0 + rw) * 512;
    const int wsw = (rw >> 1) & 3;
    const int wp0 = (0 ^ wsw) * 8, wp1 = (1 ^ wsw) * 8;
    const int wp2 = (2 ^ wsw) * 8, wp3 = (3 ^ wsw) * 8;

    f32x4 acc[8][4];
#pragma unroll
    for (int i = 0; i < 8; ++i)
#pragma unroll
        for (int j = 0; j < 4; ++j) acc[i][j] = (f32x4)0.f;

    // ---- prologue: tile 0 into buf0; W regs advance to tile 1 ----
    float4 w0 = *reinterpret_cast<const float4*>(Wg + 0);
    float4 w1 = *reinterpret_cast<const float4*>(Wg + 4);
    float4 w2 = *reinterpret_cast<const float4*>(Wg + 8);
    float4 w3 = *reinterpret_cast<const float4*>(Wg + 12);
    float4 w4 = *reinterpret_cast<const float4*>(Wg + 16);
    float4 w5 = *reinterpret_cast<const float4*>(Wg + 20);
    float4 w6 = *reinterpret_cast<const float4*>(Wg + 24);
    float4 w7 = *reinterpret_cast<const float4*>(Wg + 28);
    {
        _Float16* b0 = lds;
        gload_lds16(gh0, b0 + s0 * 512);
        gload_lds16(gh1, b0 + (s0 + 1) * 512);
        gload_lds16(gl0, b0 + 4096 + s0 * 512);
        gload_lds16(gl1, b0 + 4096 + (s0 + 1) * 512);
        *reinterpret_cast<half8*>(b0 + 8192 + rw * 32 + wp0) = pk8(w0, w1);
        *reinterpret_cast<half8*>(b0 + 8192 + rw * 32 + wp1) = pk8(w2, w3);
        *reinterpret_cast<half8*>(b0 + 8192 + rw * 32 + wp2) = pk8(w4, w5);
        *reinterpret_cast<half8*>(b0 + 8192 + rw * 32 + wp3) = pk8(w6, w7);
    }
    w0 = *reinterpret_cast<const float4*>(Wg + 32);
    w1 = *reinterpret_cast<const float4*>(Wg + 36);
    w2 = *reinterpret_cast<const float4*>(Wg + 40);
    w3 = *reinterpret_cast<const float4*>(Wg + 44);
    w4 = *reinterpret_cast<const float4*>(Wg + 48);
    w5 = *reinterpret_cast<const float4*>(Wg + 52);
    w6 = *reinterpret_cast<const float4*>(Wg + 56);
    w7 = *reinterpret_cast<const float4*>(Wg + 60);
    asm volatile("s_waitcnt vmcnt(8) lgkmcnt(0)" ::: "memory");
    __builtin_amdgcn_sched_barrier(0);
    __builtin_amdgcn_s_barrier();
    __builtin_amdgcn_sched_barrier(0);

#define FRAG_MFMA(BC)                                                          \
    do {                                                                       \
        half8 wv[4];                                                           \
        _Pragma("unroll")                                                      \
        for (int nf = 0; nf < 4; ++nf) {                                       \
            const int rb = wid * 64 + nf * 16 + l15;                           \
            const int ph = (kq ^ ((rb >> 1) & 3)) * 8;                         \
            wv[nf] = *reinterpret_cast<const half8*>((BC) + 8192 + rb * 32 + ph);\
        }                                                                      \
        _Pragma("unroll")                                                      \
        for (int mf = 0; mf < 8; ++mf) {                                       \
            const int r  = mf * 16 + l15;                                      \
            const int ph = (kq ^ ((r >> 1) & 3)) * 8;                          \
            const half8 ahf = *reinterpret_cast<const half8*>((BC) + r * 32 + ph);\
            const half8 alf = *reinterpret_cast<const half8*>((BC) + 4096 + r * 32 + ph);\
            _Pragma("unroll")                                                  \
            for (int nf = 0; nf < 4; ++nf)                                     \
                acc[mf][nf] = __builtin_amdgcn_mfma_f32_16x16x32_f16(          \
                    ahf, wv[nf], acc[mf][nf], 0, 0, 0);                        \
            _Pragma("unroll")                                                  \
            for (int nf = 0; nf < 4; ++nf)                                     \
                acc[mf][nf] = __builtin_amdgcn_mfma_f32_16x16x32_f16(          \
                    alf, wv[nf], acc[mf][nf], 0, 0, 0);                        \
        }                                                                      \
    } while (0)

#pragma unroll 1
    for (int t = 0; t < 15; ++t) {
        const int cur = t & 1;
        const _Float16* bc = lds + cur * 16384;
        _Float16* bn = lds + (cur ^ 1) * 16384;
        const int kbN = (t + 1) * 32;

        // 1. issue A glds for k-tile t+1 (whole step to land)
        gload_lds16(gh0 + kbN, bn + s0 * 512);
        gload_lds16(gh1 + kbN, bn + (s0 + 1) * 512);
        gload_lds16(gl0 + kbN, bn + 4096 + s0 * 512);
        gload_lds16(gl1 + kbN, bn + 4096 + (s0 + 1) * 512);

        // 2. compute current tile
        FRAG_MFMA(bc);

        // 3. cvt W (regs hold k-tile t+1) -> bn
        *reinterpret_cast<half8*>(bn + 8192 + rw * 32 + wp0) = pk8(w0, w1);
        *reinterpret_cast<half8*>(bn + 8192 + rw * 32 + wp1) = pk8(w2, w3);
        *reinterpret_cast<half8*>(bn + 8192 + rw * 32 + wp2) = pk8(w4, w5);
        *reinterpret_cast<half8*>(bn + 8192 + rw * 32 + wp3) = pk8(w6, w7);

        // 4. W regs <- k-tile t+2 (needed through t=13 -> tile 15; t=14 dead)
        {
            const int kb2 = (t < 14) ? (t + 2) * 32 : 0;
            w0 = *reinterpret_cast<const float4*>(Wg + kb2 + 0);
            w1 = *reinterpret_cast<const float4*>(Wg + kb2 + 4);
            w2 = *reinterpret_cast<const float4*>(Wg + kb2 + 8);
            w3 = *reinterpret_cast<const float4*>(Wg + kb2 + 12);
            w4 = *reinterpret_cast<const float4*>(Wg + kb2 + 16);
            w5 = *reinterpret_cast<const float4*>(Wg + kb2 + 20);
            w6 = *reinterpret_cast<const float4*>(Wg + kb2 + 24);
            w7 = *reinterpret_cast<const float4*>(Wg + kb2 + 28);
        }
        // 5. counted drain: 4 glds land; 8 W loads stay in flight
        asm volatile("s_waitcnt vmcnt(8) lgkmcnt(0)" ::: "memory");
        __builtin_amdgcn_sched_barrier(0);
        __builtin_amdgcn_s_barrier();
        __builtin_amdgcn_sched_barrier(0);
    }
    // t = 15: compute-only (buf1)
    FRAG_MFMA(lds + 16384);
#undef FRAG_MFMA

    // epilogue: C/D layout col = lane&15, row = (lane>>4)*4 + j (verified)
    float bv[4];
#pragma unroll
    for (int nf = 0; nf < 4; ++nf)
        bv[nf] = bias[col0 + wid * 64 + nf * 16 + l15];

#pragma unroll
    for (int mf = 0; mf < 8; ++mf)
#pragma unroll
        for (int nf = 0; nf < 4; ++nf) {
            const int c = col0 + wid * 64 + nf * 16 + l15;
#pragma unroll
            for (int j = 0; j < 4; ++j) {
                const int r = row0 + mf * 16 + kq * 4 + j;
                C[(size_t)r * 1536 + c] = acc[mf][nf][j] + bv[nf];
            }
        }
}

// ---------------------------------------------------------------------------
// k2: scrambled elementwise softmax (verified round 1, unchanged)
// ---------------------------------------------------------------------------
__global__ __launch_bounds__(256) void attn_scramble(
    const float* __restrict__ qkv, float* __restrict__ out)
{
    __shared__ float Ks[64][65];
    const int bid = blockIdx.x;
    const int hw6 = bid & 63;
    const int n   = (bid >> 6) & 7;
    const int b   = bid >> 9;
    const int kn  = (n + 7) & 7;
    const int t   = threadIdx.x;
    {
        const int hwlo = t & 63;
        const int d0   = t >> 6;
#pragma unroll
        for (int s = 0; s < 16; ++s) {
            const int dp = s * 4 + d0;
            Ks[dp][hwlo] =
                qkv[(size_t)(b * 4096 + dp * 64 + hw6) * 1536 + 512 + kn * 64 + hwlo];
        }
    }
    __syncthreads();
    const int row = t >> 2;
    const int tl  = t & 3;
    const size_t rbase = (size_t)(b * 4096 + hw6 * 64 + row) * 1536;
    float s[16];
    {
        const float* qp = qkv + rbase + n * 64 + tl * 16;
        float q[16];
#pragma unroll
        for (int u = 0; u < 4; ++u)
            *reinterpret_cast<float4*>(&q[u * 4]) =
                *reinterpret_cast<const float4*>(qp + u * 4);
        float m = -1e30f;
#pragma unroll
        for (int u = 0; u < 16; ++u) {
            s[u] = 0.125f * q[u] * Ks[tl * 16 + u][row];
            m = fmaxf(m, s[u]);
        }
        m = fmaxf(m, __shfl_xor(m, 1));
        m = fmaxf(m, __shfl_xor(m, 2));
        float sum = 0.f;
#pragma unroll
        for (int u = 0; u < 16; ++u) {
            s[u] = __expf(s[u] - m);
            sum += s[u];
        }
        sum += __shfl_xor(sum, 1);
        sum += __shfl_xor(sum, 2);
        const float inv = 1.0f / sum;
#pragma unroll
        for (int u = 0; u < 16; ++u) s[u] *= inv;
    }
    const float* vp = qkv + rbase + 1024 + kn * 64 + tl * 16;
    const int vb = b >> 3, fr = b & 7;
    float* op = out +
        ((size_t)(((vb * 8 + (hw6 >> 3)) * 64 + ((hw6 & 7) * 8 + (row >> 3))) * 64 +
                  ((row & 7) * 8 + n)) * 512) + fr * 64 + tl * 16;
#pragma unroll
    for (int u = 0; u < 4; ++u) {
        const float4 v = *reinterpret_cast<const float4*>(vp + u * 4);
        float4 o;
        o.x = s[u * 4 + 0] * v.x;
        o.y = s[u * 4 + 1] * v.y;
        o.z = s[u * 4 + 2] * v.z;
        o.w = s[u * 4 + 3] * v.w;
        *reinterpret_cast<float4*>(op + u * 4) = o;
    }
}

// ---------------------------------------------------------------------------
extern "C" void kernel_launch(void* const* d_in, const int* in_sizes, int n_in,
                              void* d_out, int out_size, void* d_ws, size_t ws_size,
                              hipStream_t stream) {
    const float* hs = (const float*)d_in[0];  // [65536,512]
    const float* w  = (const float*)d_in[1];  // [1536,512]
    const float* bq = (const float*)d_in[2];  // [1536]
    float* out = (float*)d_out;
    float* qkv = (float*)d_ws;                // 402,653,184 B (fits: r1+ ran)

    // d_out as scratch for the A split: Ah | Al, 67,108,864 B each (exact fit)
    _Float16* Asp_h = (_Float16*)d_out;
    _Float16* Asp_l = Asp_h + 33554432;       // 65536*512

    split_a<<<16384, 256, 0, stream>>>(hs, Asp_h, Asp_l);
    gemm_qkv_w256<<<3072, 256, 0, stream>>>(Asp_h, Asp_l, w, bq, qkv);
    attn_scramble<<<8192, 256, 0, stream>>>(qkv, out);
}

// Round 13
// 327.659 us; speedup vs baseline: 1.4608x; 1.4608x over previous
//
#include <hip/hip_runtime.h>
#include <math.h>

// Pipeline (d_out doubles as scratch: Ah fp16 67MB + Wh fp16 1.5MB < 134MB):
//   k0 cvt_fp16(A):  A fp32 [65536,512] -> Ah fp16 (row-major) in d_out
//   k0b cvt_fp16(W): w_qkv fp32 [1536,512] -> Wh fp16 in d_out+67MB
//   k1 gemm:         qkv[65536,1536] = Ah @ Wh^T + bias  (fp32, in d_ws)
//                    single-term fp16 MFMA (error budget: W fp16 already
//                    dominated r10's 9.77e-4; adding A fp16 -> ~1.4-2e-3,
//                    threshold 5.7e-3). Pure glds+ds_read+MFMA loop (m97).
//   k2 scramble:     qkv -> out (overwrites d_out; verified round 1)

typedef _Float16 half8 __attribute__((ext_vector_type(8)));
typedef __fp16 fp16x2 __attribute__((ext_vector_type(2)));
typedef float f32x4 __attribute__((ext_vector_type(4)));

__device__ __forceinline__ half8 pk8(const float4 x, const float4 y) {
    fp16x2 a = __builtin_amdgcn_cvt_pkrtz(x.x, x.y);
    fp16x2 b = __builtin_amdgcn_cvt_pkrtz(x.z, x.w);
    fp16x2 c = __builtin_amdgcn_cvt_pkrtz(y.x, y.y);
    fp16x2 d = __builtin_amdgcn_cvt_pkrtz(y.z, y.w);
    half8 r;
    r[0] = (_Float16)a[0]; r[1] = (_Float16)a[1];
    r[2] = (_Float16)b[0]; r[3] = (_Float16)b[1];
    r[4] = (_Float16)c[0]; r[5] = (_Float16)c[1];
    r[6] = (_Float16)d[0]; r[7] = (_Float16)d[1];
    return r;
}

__device__ __forceinline__ void gload_lds16(const void* g, void* l) {
    __builtin_amdgcn_global_load_lds(
        (const __attribute__((address_space(1))) unsigned int*)g,
        (__attribute__((address_space(3))) unsigned int*)l, 16, 0, 0);
}

// ---------------------------------------------------------------------------
// k0: streaming fp32 -> fp16 (RTZ via cvt_pkrtz; row-major preserved)
// ---------------------------------------------------------------------------
__global__ __launch_bounds__(256) void cvt_fp16(
    const float* __restrict__ src, _Float16* __restrict__ dst)
{
    const size_t i = (size_t)blockIdx.x * 256 + threadIdx.x;   // 8 floats each
    const float4 x = *reinterpret_cast<const float4*>(src + i * 8);
    const float4 y = *reinterpret_cast<const float4*>(src + i * 8 + 4);
    *reinterpret_cast<half8*>(dst + i * 8) = pk8(x, y);
}

// ---------------------------------------------------------------------------
// k1: C[65536,1536] = Ah @ Wh^T + bias.  BM=BN=128, BK=32, 4 waves (2x2).
// LDS/buffer (halfwords): Ah [0,4096), Wh [4096,8192); dbuf 32KB total.
// Swizzle: 16B chunk c of row r at phys c ^ ((r>>1)&3) — measured 0 conflicts.
// Both tiles staged via global_load_lds with the XOR applied on the per-lane
// GLOBAL source (rule 21). Loop body: 4 glds + 8 ds_read_b128 + 16 MFMA.
// ---------------------------------------------------------------------------
__global__ __launch_bounds__(256, 4) void gemm_qkv_1t(
    const _Float16* __restrict__ Ah, const _Float16* __restrict__ Wh,
    const float* __restrict__ bias, float* __restrict__ C)
{
    __shared__ __align__(16) _Float16 lds[16384];   // 2 x 16 KB

    const int lin = blockIdx.x;                      // 6144 blocks, %8==0
    const int swz = (lin & 7) * 768 + (lin >> 3);
    const int nt = swz % 12, mt = swz / 12;          // nt fastest: A L2-reuse
    const int row0 = mt * 128, col0 = nt * 128;

    const int tid = threadIdx.x, wid = tid >> 6, lane = tid & 63;
    const int wm = wid >> 1, wn = wid & 1, l15 = lane & 15, kq = lane >> 4;

    // staging: wave wid owns 1KB segs {s0, s0+1} of BOTH the A and W tiles.
    // Lane j writes LDS seg*1024 + j*16 linearly; tile slot row = seg*16+(j>>2),
    // phys chunk = j&3; source holds logical chunk (j&3) ^ ((row>>1)&3).
    const int s0  = wid * 2;
    const int rA0 = s0 * 16 + (lane >> 2);
    const int rA1 = rA0 + 16;
    const int c0  = (lane & 3) ^ ((rA0 >> 1) & 3);
    const int c1  = (lane & 3) ^ ((rA1 >> 1) & 3);
    const _Float16* ga0 = Ah + (size_t)(row0 + rA0) * 512 + c0 * 8;
    const _Float16* ga1 = Ah + (size_t)(row0 + rA1) * 512 + c1 * 8;
    const _Float16* gw0 = Wh + (size_t)(col0 + rA0) * 512 + c0 * 8;
    const _Float16* gw1 = Wh + (size_t)(col0 + rA1) * 512 + c1 * 8;

    f32x4 acc[4][4];
#pragma unroll
    for (int i = 0; i < 4; ++i)
#pragma unroll
        for (int j = 0; j < 4; ++j) acc[i][j] = (f32x4)0.f;

    // ---- prologue: k-tile 0 into buf0 ----
    {
        _Float16* b0 = lds;
        gload_lds16(ga0, b0 + s0 * 512);
        gload_lds16(ga1, b0 + (s0 + 1) * 512);
        gload_lds16(gw0, b0 + 4096 + s0 * 512);
        gload_lds16(gw1, b0 + 4096 + (s0 + 1) * 512);
    }
    asm volatile("s_waitcnt vmcnt(0) lgkmcnt(0)" ::: "memory");
    __builtin_amdgcn_sched_barrier(0);
    __builtin_amdgcn_s_barrier();
    __builtin_amdgcn_sched_barrier(0);

#define FRAG_MFMA(BC)                                                          \
    do {                                                                       \
        half8 ah[4];                                                           \
        _Pragma("unroll")                                                      \
        for (int mf = 0; mf < 4; ++mf) {                                       \
            const int r  = wm * 64 + mf * 16 + l15;                            \
            const int ph = (kq ^ ((r >> 1) & 3)) * 8;                          \
            ah[mf] = *reinterpret_cast<const half8*>((BC) + r * 32 + ph);      \
        }                                                                      \
        _Pragma("unroll")                                                      \
        for (int nf = 0; nf < 4; ++nf) {                                       \
            const int rb = wn * 64 + nf * 16 + l15;                            \
            const int ph = (kq ^ ((rb >> 1) & 3)) * 8;                         \
            const half8 wv =                                                   \
                *reinterpret_cast<const half8*>((BC) + 4096 + rb * 32 + ph);   \
            _Pragma("unroll")                                                  \
            for (int mf = 0; mf < 4; ++mf)                                     \
                acc[mf][nf] = __builtin_amdgcn_mfma_f32_16x16x32_f16(          \
                    ah[mf], wv, acc[mf][nf], 0, 0, 0);                         \
        }                                                                      \
    } while (0)

#pragma unroll 1
    for (int t = 0; t < 15; ++t) {
        const int cur = t & 1;
        const _Float16* bc = lds + cur * 8192;
        _Float16* bn = lds + (cur ^ 1) * 8192;
        const int kbN = (t + 1) * 32;

        // issue next tile's 4 glds; they drain under FRAG, at the barrier
        gload_lds16(ga0 + kbN, bn + s0 * 512);
        gload_lds16(ga1 + kbN, bn + (s0 + 1) * 512);
        gload_lds16(gw0 + kbN, bn + 4096 + s0 * 512);
        gload_lds16(gw1 + kbN, bn + 4096 + (s0 + 1) * 512);

        FRAG_MFMA(bc);

        asm volatile("s_waitcnt vmcnt(0) lgkmcnt(0)" ::: "memory");
        __builtin_amdgcn_sched_barrier(0);
        __builtin_amdgcn_s_barrier();
        __builtin_amdgcn_sched_barrier(0);
    }
    // t = 15: compute-only (buf1)
    FRAG_MFMA(lds + 8192);
#undef FRAG_MFMA

    // epilogue: C/D layout col = lane&15, row = (lane>>4)*4 + j (verified)
    float bv[4];
#pragma unroll
    for (int nf = 0; nf < 4; ++nf)
        bv[nf] = bias[col0 + wn * 64 + nf * 16 + l15];

#pragma unroll
    for (int mf = 0; mf < 4; ++mf)
#pragma unroll
        for (int nf = 0; nf < 4; ++nf) {
            const int c = col0 + wn * 64 + nf * 16 + l15;
#pragma unroll
            for (int j = 0; j < 4; ++j) {
                const int r = row0 + wm * 64 + mf * 16 + kq * 4 + j;
                C[(size_t)r * 1536 + c] = acc[mf][nf][j] + bv[nf];
            }
        }
}

// ---------------------------------------------------------------------------
// k2: scrambled elementwise softmax (verified round 1, unchanged)
// ---------------------------------------------------------------------------
__global__ __launch_bounds__(256) void attn_scramble(
    const float* __restrict__ qkv, float* __restrict__ out)
{
    __shared__ float Ks[64][65];
    const int bid = blockIdx.x;
    const int hw6 = bid & 63;
    const int n   = (bid >> 6) & 7;
    const int b   = bid >> 9;
    const int kn  = (n + 7) & 7;
    const int t   = threadIdx.x;
    {
        const int hwlo = t & 63;
        const int d0   = t >> 6;
#pragma unroll
        for (int s = 0; s < 16; ++s) {
            const int dp = s * 4 + d0;
            Ks[dp][hwlo] =
                qkv[(size_t)(b * 4096 + dp * 64 + hw6) * 1536 + 512 + kn * 64 + hwlo];
        }
    }
    __syncthreads();
    const int row = t >> 2;
    const int tl  = t & 3;
    const size_t rbase = (size_t)(b * 4096 + hw6 * 64 + row) * 1536;
    float s[16];
    {
        const float* qp = qkv + rbase + n * 64 + tl * 16;
        float q[16];
#pragma unroll
        for (int u = 0; u < 4; ++u)
            *reinterpret_cast<float4*>(&q[u * 4]) =
                *reinterpret_cast<const float4*>(qp + u * 4);
        float m = -1e30f;
#pragma unroll
        for (int u = 0; u < 16; ++u) {
            s[u] = 0.125f * q[u] * Ks[tl * 16 + u][row];
            m = fmaxf(m, s[u]);
        }
        m = fmaxf(m, __shfl_xor(m, 1));
        m = fmaxf(m, __shfl_xor(m, 2));
        float sum = 0.f;
#pragma unroll
        for (int u = 0; u < 16; ++u) {
            s[u] = __expf(s[u] - m);
            sum += s[u];
        }
        sum += __shfl_xor(sum, 1);
        sum += __shfl_xor(sum, 2);
        const float inv = 1.0f / sum;
#pragma unroll
        for (int u = 0; u < 16; ++u) s[u] *= inv;
    }
    const float* vp = qkv + rbase + 1024 + kn * 64 + tl * 16;
    const int vb = b >> 3, fr = b & 7;
    float* op = out +
        ((size_t)(((vb * 8 + (hw6 >> 3)) * 64 + ((hw6 & 7) * 8 + (row >> 3))) * 64 +
                  ((row & 7) * 8 + n)) * 512) + fr * 64 + tl * 16;
#pragma unroll
    for (int u = 0; u < 4; ++u) {
        const float4 v = *reinterpret_cast<const float4*>(vp + u * 4);
        float4 o;
        o.x = s[u * 4 + 0] * v.x;
        o.y = s[u * 4 + 1] * v.y;
        o.z = s[u * 4 + 2] * v.z;
        o.w = s[u * 4 + 3] * v.w;
        *reinterpret_cast<float4*>(op + u * 4) = o;
    }
}

// ---------------------------------------------------------------------------
extern "C" void kernel_launch(void* const* d_in, const int* in_sizes, int n_in,
                              void* d_out, int out_size, void* d_ws, size_t ws_size,
                              hipStream_t stream) {
    const float* hs = (const float*)d_in[0];  // [65536,512]
    const float* w  = (const float*)d_in[1];  // [1536,512]
    const float* bq = (const float*)d_in[2];  // [1536]
    float* out = (float*)d_out;
    float* qkv = (float*)d_ws;                // 402,653,184 B (fits: r1+ ran)

    // d_out as scratch: Ah (67,108,864 B) | Wh (1,572,864 B)
    _Float16* Asp = (_Float16*)d_out;
    _Float16* Wsp = Asp + 33554432;           // 65536*512

    cvt_fp16<<<16384, 256, 0, stream>>>(hs, Asp);   // A: 65536*512/8 threads
    cvt_fp16<<<384, 256, 0, stream>>>(w, Wsp);      // W: 1536*512/8 threads
    gemm_qkv_1t<<<6144, 256, 0, stream>>>(Asp, Wsp, bq, qkv);
    attn_scramble<<<8192, 256, 0, stream>>>(qkv, out);
}